// Round 8
// baseline (1086.338 us; speedup 1.0000x reference)
//
#include <hip/hip_runtime.h>
#include <hip/hip_bf16.h>
#include <math.h>

// Problem constants
#define BB 32
#define TT 512
#define HH 2048
#define KK 128

// -------------------- Kernel A: logits = hiddens @ W + b --------------------
// 256 blocks x 512 threads, in-block split-K (4 wave-groups x K=512).
__global__ __launch_bounds__(512) void gemm_k(const float* __restrict__ hid,
                                              const float* __restrict__ Wm,
                                              const float* __restrict__ bias,
                                              float* __restrict__ logits,
                                              float* __restrict__ loss_slot) {
    __shared__ union {
        struct { float As[4][16][72]; float Bs[4][16][132]; } s;  // 52.2 KB
        float4 red[16][128];                                      // 32 KB
    } sm;
    const int tid = threadIdx.x, bid = blockIdx.x;
    if (bid == 0 && tid == 0) loss_slot[0] = 0.0f;
    const int g = tid >> 7, lt = tid & 127;
    const int rowBase = bid * 64;
    const int rowg = lt >> 4, colg = lt & 15;
    const int arow = lt >> 1, ahq = lt & 1;  // A staging: row, h-half

    float acc[8][8];
#pragma unroll
    for (int i = 0; i < 8; i++)
#pragma unroll
        for (int j = 0; j < 8; j++) acc[i][j] = 0.0f;

    const float* hA = hid + (size_t)(rowBase + arow) * HH + g * 512 + ahq * 8;

    float4 a0, a1, bv[4];
    {
        const int h0 = g * 512;
        a0 = *(const float4*)(hA);
        a1 = *(const float4*)(hA + 4);
#pragma unroll
        for (int r = 0; r < 4; ++r) {
            int idx = r * 128 + lt;
            bv[r] = *(const float4*)(Wm + (size_t)(h0 + (idx >> 5)) * KK + (idx & 31) * 4);
        }
    }

    for (int it = 0; it < 32; ++it) {
        __syncthreads();
        const int hb = ahq * 8;
        sm.s.As[g][hb + 0][arow] = a0.x;
        sm.s.As[g][hb + 1][arow] = a0.y;
        sm.s.As[g][hb + 2][arow] = a0.z;
        sm.s.As[g][hb + 3][arow] = a0.w;
        sm.s.As[g][hb + 4][arow] = a1.x;
        sm.s.As[g][hb + 5][arow] = a1.y;
        sm.s.As[g][hb + 6][arow] = a1.z;
        sm.s.As[g][hb + 7][arow] = a1.w;
#pragma unroll
        for (int r = 0; r < 4; ++r) {
            int idx = r * 128 + lt;
            *(float4*)&sm.s.Bs[g][idx >> 5][(idx & 31) * 4] = bv[r];
        }
        __syncthreads();
        if (it + 1 < 32) {
            const int h0 = g * 512 + (it + 1) * 16;
            a0 = *(const float4*)(hA + (it + 1) * 16);
            a1 = *(const float4*)(hA + (it + 1) * 16 + 4);
#pragma unroll
            for (int r = 0; r < 4; ++r) {
                int idx = r * 128 + lt;
                bv[r] = *(const float4*)(Wm + (size_t)(h0 + (idx >> 5)) * KK + (idx & 31) * 4);
            }
        }
#pragma unroll
        for (int h = 0; h < 16; ++h) {
            float4 aL = *(const float4*)&sm.s.As[g][h][rowg * 8];
            float4 aH = *(const float4*)&sm.s.As[g][h][rowg * 8 + 4];
            float4 b0 = *(const float4*)&sm.s.Bs[g][h][colg * 4];
            float4 b1 = *(const float4*)&sm.s.Bs[g][h][64 + colg * 4];
            float ar[8] = {aL.x, aL.y, aL.z, aL.w, aH.x, aH.y, aH.z, aH.w};
            float br[8] = {b0.x, b0.y, b0.z, b0.w, b1.x, b1.y, b1.z, b1.w};
#pragma unroll
            for (int i = 0; i < 8; i++)
#pragma unroll
                for (int j = 0; j < 8; j++) acc[i][j] = fmaf(ar[i], br[j], acc[i][j]);
        }
    }
    __syncthreads();
    for (int gp = 1; gp <= 3; ++gp) {
        if (g == gp) {
#pragma unroll
            for (int i = 0; i < 8; ++i) {
                sm.red[i * 2][lt] = make_float4(acc[i][0], acc[i][1], acc[i][2], acc[i][3]);
                sm.red[i * 2 + 1][lt] = make_float4(acc[i][4], acc[i][5], acc[i][6], acc[i][7]);
            }
        }
        __syncthreads();
        if (g == 0) {
#pragma unroll
            for (int i = 0; i < 8; ++i) {
                float4 r0 = sm.red[i * 2][lt];
                float4 r1 = sm.red[i * 2 + 1][lt];
                acc[i][0] += r0.x; acc[i][1] += r0.y; acc[i][2] += r0.z; acc[i][3] += r0.w;
                acc[i][4] += r1.x; acc[i][5] += r1.y; acc[i][6] += r1.z; acc[i][7] += r1.w;
            }
        }
        __syncthreads();
    }
    if (g == 0) {
        float4 bb0 = *(const float4*)(bias + colg * 4);
        float4 bb1 = *(const float4*)(bias + 64 + colg * 4);
#pragma unroll
        for (int i = 0; i < 8; ++i) {
            int row = rowBase + rowg * 8 + i;
            *(float4*)(logits + (size_t)row * KK + colg * 4) =
                make_float4(acc[i][0] + bb0.x, acc[i][1] + bb0.y, acc[i][2] + bb0.z, acc[i][3] + bb0.w);
            *(float4*)(logits + (size_t)row * KK + 64 + colg * 4) =
                make_float4(acc[i][4] + bb1.x, acc[i][5] + bb1.y, acc[i][6] + bb1.z, acc[i][7] + bb1.w);
        }
    }
}

// -------------------- Kernel B: sequential scans, SINGLE WAVE per sequence ----
// 64 blocks x 64 threads, one wave per scan. Lane (q=lane&31, h=lane>>5):
// owns cols 4q..4q+3, k-half [64h,64h+64). One shfl_xor(32) per column
// combines k-halves (4 shfls issued together -> single latency). Alpha lives
// in a 512B LDS buffer; same-wave ds_write -> ds_read needs only lgkmcnt —
// NO __syncthreads in the 511-step loop. Transitions resident in 256 VGPRs.
// Emissions: register ring one 8-step chunk ahead. Viterbi history:
// fire-and-forget global dwordx4 per step.
__global__ __launch_bounds__(64, 1) void scan_k(const float* __restrict__ logits,
                                                const int* __restrict__ mask,
                                                const int* __restrict__ labels,
                                                const float* __restrict__ startT,
                                                const float* __restrict__ endT,
                                                const float* __restrict__ trans,
                                                float* __restrict__ shist,
                                                float* __restrict__ out) {
    __shared__ float sal[128];
    const int lane = threadIdx.x;
    const int bid = blockIdx.x;
    const float L2E = 1.4426950408889634f;
    const int q = lane & 31;   // column quad: cols 4q..4q+3
    const int h = lane >> 5;   // k half: k in [64h, 64h+64)
    const int j0 = 4 * q;

    if (bid < BB) {
        // ---------- forward (log-partition), exp domain ----------
        const int b = bid;
        const float* lrow = logits + (size_t)b * TT * KK;
        unsigned long long mb[8];
#pragma unroll
        for (int c = 0; c < 8; ++c) mb[c] = __ballot(mask[b * TT + c * 64 + lane] != 0);

        float2 Vp0[32], Vp1[32], Vp2[32], Vp3[32];
#pragma unroll
        for (int p = 0; p < 32; ++p) {
            float4 ra = *(const float4*)&trans[(size_t)(h * 64 + 2 * p) * KK + j0];
            float4 rb = *(const float4*)&trans[(size_t)(h * 64 + 2 * p + 1) * KK + j0];
            Vp0[p] = make_float2(exp2f(ra.x * L2E), exp2f(rb.x * L2E));
            Vp1[p] = make_float2(exp2f(ra.y * L2E), exp2f(rb.y * L2E));
            Vp2[p] = make_float2(exp2f(ra.z * L2E), exp2f(rb.z * L2E));
            Vp3[p] = make_float2(exp2f(ra.w * L2E), exp2f(rb.w * L2E));
        }
        // init t=0
        float4 st4 = *(const float4*)(startT + j0);
        float4 e0 = *(const float4*)(lrow + j0);
        float OFF = (startT[0] + lrow[0]) * L2E;   // uniform across lanes
        float S0 = exp2f((st4.x + e0.x) * L2E - OFF);
        float S1 = exp2f((st4.y + e0.y) * L2E - OFF);
        float S2 = exp2f((st4.z + e0.z) * L2E - OFF);
        float S3 = exp2f((st4.w + e0.w) * L2E - OFF);
        float s0bc = 1.0f;  // S of col 0 (normalizer), stale-by-one
        if (h == 0) *(float4*)&sal[j0] = make_float4(S0, S1, S2, S3);

        float4 emc[8], emn[8];
#pragma unroll
        for (int d = 0; d < 8; ++d) emc[d] = *(const float4*)(lrow + (size_t)d * KK + j0);

        for (int c = 0; c < 64; ++c) {
            if (c < 63) {
#pragma unroll
                for (int d = 0; d < 8; ++d)
                    emn[d] = *(const float4*)(lrow + (size_t)((c + 1) * 8 + d) * KK + j0);
            }
#pragma unroll
            for (int r = 0; r < 8; ++r) {
                const int t = c * 8 + r;
                if (t > 0 && ((mb[t >> 6] >> (t & 63)) & 1ull)) {
                    float rinv = __builtin_amdgcn_rcpf(s0bc);
                    OFF += log2f(s0bc);   // off-chain (final logZ only)
                    float2 a0 = make_float2(0.f, 0.f), a1 = make_float2(0.f, 0.f);
                    float2 a2 = make_float2(0.f, 0.f), a3 = make_float2(0.f, 0.f);
                    const float* base = &sal[h * 64];
#pragma unroll
                    for (int i = 0; i < 16; ++i) {
                        float4 U = *(const float4*)(base + 4 * i);
                        a0.x = fmaf(U.x, Vp0[2 * i].x, a0.x);     a0.y = fmaf(U.y, Vp0[2 * i].y, a0.y);
                        a1.x = fmaf(U.x, Vp1[2 * i].x, a1.x);     a1.y = fmaf(U.y, Vp1[2 * i].y, a1.y);
                        a2.x = fmaf(U.x, Vp2[2 * i].x, a2.x);     a2.y = fmaf(U.y, Vp2[2 * i].y, a2.y);
                        a3.x = fmaf(U.x, Vp3[2 * i].x, a3.x);     a3.y = fmaf(U.y, Vp3[2 * i].y, a3.y);
                        a0.x = fmaf(U.z, Vp0[2 * i + 1].x, a0.x); a0.y = fmaf(U.w, Vp0[2 * i + 1].y, a0.y);
                        a1.x = fmaf(U.z, Vp1[2 * i + 1].x, a1.x); a1.y = fmaf(U.w, Vp1[2 * i + 1].y, a1.y);
                        a2.x = fmaf(U.z, Vp2[2 * i + 1].x, a2.x); a2.y = fmaf(U.w, Vp2[2 * i + 1].y, a2.y);
                        a3.x = fmaf(U.z, Vp3[2 * i + 1].x, a3.x); a3.y = fmaf(U.w, Vp3[2 * i + 1].y, a3.y);
                    }
                    float w0 = a0.x + a0.y, w1 = a1.x + a1.y;
                    float w2 = a2.x + a2.y, w3 = a3.x + a3.y;
                    // combine k-halves: 4 shfls issued together (one latency)
                    float x0 = __shfl_xor(w0, 32, 64), x1 = __shfl_xor(w1, 32, 64);
                    float x2 = __shfl_xor(w2, 32, 64), x3 = __shfl_xor(w3, 32, 64);
                    w0 += x0; w1 += x1; w2 += x2; w3 += x3;
                    float4 e = emc[r];
                    S0 = w0 * (exp2f(e.x * L2E) * rinv);
                    S1 = w1 * (exp2f(e.y * L2E) * rinv);
                    S2 = w2 * (exp2f(e.z * L2E) * rinv);
                    S3 = w3 * (exp2f(e.w * L2E) * rinv);
                    s0bc = __shfl(S0, 0, 64);   // lane 0 owns col 0; consumed next step
                    if (h == 0) *(float4*)&sal[j0] = make_float4(S0, S1, S2, S3);
                }
            }
#pragma unroll
            for (int d = 0; d < 8; ++d) emc[d] = emn[d];
        }

        // final logZ + gold score
        float4 et = *(const float4*)(endT + j0);
        float v0 = log2f(S0) + et.x * L2E;
        float v1 = log2f(S1) + et.y * L2E;
        float v2 = log2f(S2) + et.z * L2E;
        float v3 = log2f(S3) + et.w * L2E;
        float mx = fmaxf(fmaxf(v0, v1), fmaxf(v2, v3));
#pragma unroll
        for (int d = 1; d < 64; d <<= 1) mx = fmaxf(mx, __shfl_xor(mx, d, 64));
        float p = (h == 0) ? (exp2f(v0 - mx) + exp2f(v1 - mx) + exp2f(v2 - mx) + exp2f(v3 - mx)) : 0.0f;
#pragma unroll
        for (int d = 1; d < 64; d <<= 1) p += __shfl_xor(p, d, 64);

        float part = 0.0f;
#pragma unroll
        for (int it = 0; it < 8; ++it) {
            int tt = lane + it * 64;
            if (tt == 0) {
                int l0 = labels[b * TT];
                part += startT[l0] + lrow[l0];
            } else if (mask[b * TT + tt]) {
                int lc = labels[b * TT + tt];
                int lp = labels[b * TT + tt - 1];
                part += trans[lp * KK + lc] + lrow[(size_t)tt * KK + lc];
            }
        }
#pragma unroll
        for (int d = 1; d < 64; d <<= 1) part += __shfl_xor(part, d, 64);

        if (lane == 0) {
            int total = 0;
#pragma unroll
            for (int c = 0; c < 8; ++c) total += __popcll(mb[c]);
            float score = part + endT[labels[b * TT + total - 1]];
            float logZ = (OFF + mx + log2f(p)) * 0.6931471805599453f;
            float llh = score - logZ;
            atomicAdd(out + BB * TT, -llh * (1.0f / 32.0f));
        }
    } else {
        // ---------- viterbi forward (max only; score history -> ws) ----------
        const int b = bid - BB;
        const float* lrow = logits + (size_t)b * TT * KK;
        float* hist = shist + (size_t)b * TT * KK;
        unsigned long long mb[8];
#pragma unroll
        for (int c = 0; c < 8; ++c) mb[c] = __ballot(mask[b * TT + c * 64 + lane] != 0);

        float2 Tp0[32], Tp1[32], Tp2[32], Tp3[32];
#pragma unroll
        for (int p = 0; p < 32; ++p) {
            float4 ra = *(const float4*)&trans[(size_t)(h * 64 + 2 * p) * KK + j0];
            float4 rb = *(const float4*)&trans[(size_t)(h * 64 + 2 * p + 1) * KK + j0];
            Tp0[p] = make_float2(ra.x, rb.x);
            Tp1[p] = make_float2(ra.y, rb.y);
            Tp2[p] = make_float2(ra.z, rb.z);
            Tp3[p] = make_float2(ra.w, rb.w);
        }
        float4 st4 = *(const float4*)(startT + j0);
        float4 e0 = *(const float4*)(lrow + j0);
        float S0 = st4.x + e0.x, S1 = st4.y + e0.y, S2 = st4.z + e0.z, S3 = st4.w + e0.w;
        if (h == 0) {
            *(float4*)&sal[j0] = make_float4(S0, S1, S2, S3);
            *(float4*)(hist + j0) = make_float4(S0, S1, S2, S3);
        }
        float4 emc[8], emn[8];
#pragma unroll
        for (int d = 0; d < 8; ++d) emc[d] = *(const float4*)(lrow + (size_t)d * KK + j0);

        for (int c = 0; c < 64; ++c) {
            if (c < 63) {
#pragma unroll
                for (int d = 0; d < 8; ++d)
                    emn[d] = *(const float4*)(lrow + (size_t)((c + 1) * 8 + d) * KK + j0);
            }
#pragma unroll
            for (int r = 0; r < 8; ++r) {
                const int t = c * 8 + r;
                if (t > 0) {
                    if ((mb[t >> 6] >> (t & 63)) & 1ull) {
                        float m0 = -3.0e38f, m1 = -3.0e38f, m2 = -3.0e38f, m3 = -3.0e38f;
                        const float* base = &sal[h * 64];
#pragma unroll
                        for (int i = 0; i < 16; ++i) {
                            float4 U = *(const float4*)(base + 4 * i);
                            float2 cA0 = make_float2(U.x + Tp0[2 * i].x, U.y + Tp0[2 * i].y);
                            float2 cA1 = make_float2(U.x + Tp1[2 * i].x, U.y + Tp1[2 * i].y);
                            float2 cA2 = make_float2(U.x + Tp2[2 * i].x, U.y + Tp2[2 * i].y);
                            float2 cA3 = make_float2(U.x + Tp3[2 * i].x, U.y + Tp3[2 * i].y);
                            m0 = fmaxf(m0, fmaxf(cA0.x, cA0.y));
                            m1 = fmaxf(m1, fmaxf(cA1.x, cA1.y));
                            m2 = fmaxf(m2, fmaxf(cA2.x, cA2.y));
                            m3 = fmaxf(m3, fmaxf(cA3.x, cA3.y));
                            float2 cB0 = make_float2(U.z + Tp0[2 * i + 1].x, U.w + Tp0[2 * i + 1].y);
                            float2 cB1 = make_float2(U.z + Tp1[2 * i + 1].x, U.w + Tp1[2 * i + 1].y);
                            float2 cB2 = make_float2(U.z + Tp2[2 * i + 1].x, U.w + Tp2[2 * i + 1].y);
                            float2 cB3 = make_float2(U.z + Tp3[2 * i + 1].x, U.w + Tp3[2 * i + 1].y);
                            m0 = fmaxf(m0, fmaxf(cB0.x, cB0.y));
                            m1 = fmaxf(m1, fmaxf(cB1.x, cB1.y));
                            m2 = fmaxf(m2, fmaxf(cB2.x, cB2.y));
                            m3 = fmaxf(m3, fmaxf(cB3.x, cB3.y));
                        }
                        float x0 = __shfl_xor(m0, 32, 64), x1 = __shfl_xor(m1, 32, 64);
                        float x2 = __shfl_xor(m2, 32, 64), x3 = __shfl_xor(m3, 32, 64);
                        m0 = fmaxf(m0, x0); m1 = fmaxf(m1, x1);
                        m2 = fmaxf(m2, x2); m3 = fmaxf(m3, x3);
                        float4 e = emc[r];
                        S0 = m0 + e.x; S1 = m1 + e.y; S2 = m2 + e.z; S3 = m3 + e.w;
                        if (h == 0) *(float4*)&sal[j0] = make_float4(S0, S1, S2, S3);
                    }
                    if (h == 0)
                        *(float4*)(hist + (size_t)t * KK + j0) = make_float4(S0, S1, S2, S3);
                }
            }
#pragma unroll
            for (int d = 0; d < 8; ++d) emc[d] = emn[d];
        }
    }
}

// -------------------- Kernel C: parallel backpointer recompute --------------------
__global__ __launch_bounds__(256) void bp_k(const float* __restrict__ shist,
                                            const float* __restrict__ trans,
                                            const int* __restrict__ mask,
                                            unsigned char* __restrict__ bp) {
    const int t = blockIdx.x + 1;
    const int tid = threadIdx.x;
    const int j = tid & 127, bg = tid >> 7;
    __shared__ float sc[BB][KK];
#pragma unroll
    for (int r = 0; r < 4; ++r) {
        int f = tid + r * 256;
        int bb2 = f >> 5, c4 = (f & 31) * 4;
        *(float4*)&sc[bb2][c4] = *(const float4*)&shist[(size_t)bb2 * TT * KK + (size_t)(t - 1) * KK + c4];
    }
    __syncthreads();
    float m[16];
    int idx[16];
#pragma unroll
    for (int c = 0; c < 16; c++) { m[c] = -3.0e38f; idx[c] = 0; }
    for (int i4 = 0; i4 < 32; ++i4) {
        const int ib = i4 * 4;
        float tr0 = trans[(ib + 0) * KK + j];
        float tr1 = trans[(ib + 1) * KK + j];
        float tr2 = trans[(ib + 2) * KK + j];
        float tr3 = trans[(ib + 3) * KK + j];
#pragma unroll
        for (int c = 0; c < 16; c++) {
            float4 s4 = *(const float4*)&sc[bg + 2 * c][ib];
            float c0 = s4.x + tr0, c1 = s4.y + tr1, c2 = s4.z + tr2, c3 = s4.w + tr3;
            if (c0 > m[c]) { m[c] = c0; idx[c] = ib; }
            if (c1 > m[c]) { m[c] = c1; idx[c] = ib + 1; }
            if (c2 > m[c]) { m[c] = c2; idx[c] = ib + 2; }
            if (c3 > m[c]) { m[c] = c3; idx[c] = ib + 3; }
        }
    }
#pragma unroll
    for (int c = 0; c < 16; c++) {
        int bb2 = bg + 2 * c;
        int v = idx[c];
        if (mask[bb2 * TT + t] == 0) v = j;
        bp[(size_t)bb2 * TT * KK + (size_t)t * KK + j] = (unsigned char)v;
    }
}

// -------------------- Kernel D: backtrace via 8-wave register relay --------------------
__global__ __launch_bounds__(512) void bt_k(const float* __restrict__ shist,
                                            const float* __restrict__ endT,
                                            const unsigned char* __restrict__ bp,
                                            float* __restrict__ out) {
    const int b = blockIdx.x;
    const int tid = threadIdx.x;
    const int lane = tid & 63, w = tid >> 6;
    __shared__ float cb[128];
    __shared__ int tagbuf[512];
    __shared__ int handoff;
    if (tid < 128) cb[tid] = shist[(size_t)b * TT * KK + (size_t)(TT - 1) * KK + tid] + endT[tid];
    __syncthreads();
    if (tid == 0) {
        float mm = cb[0];
        int bi = 0;
        for (int i = 1; i < 128; i++)
            if (cb[i] > mm) { mm = cb[i]; bi = i; }
        tagbuf[TT - 1] = bi;
        handoff = bi;
    }
    unsigned int reg[64];
    const unsigned char* bpb = bp + (size_t)b * TT * KK;
#pragma unroll
    for (int r = 0; r < 64; r++) {
        int t_row = w * 64 + 1 + r;
        unsigned int v = 0;
        if (t_row < TT) v = *(const unsigned short*)(bpb + (size_t)t_row * KK + lane * 2);
        reg[r] = v;
    }
    __syncthreads();
    for (int ph = 7; ph >= 0; --ph) {
        if (w == ph) {
            int tag = handoff;
#pragma unroll
            for (int r = 63; r >= 0; --r) {
                int t_row = ph * 64 + 1 + r;
                if (t_row < TT) {
                    unsigned int vv = (unsigned int)__shfl((int)reg[r], tag >> 1, 64);
                    tag = (int)((vv >> ((tag & 1) * 8)) & 0xffu);
                    if (lane == 0) tagbuf[t_row - 1] = tag;
                }
            }
            if (lane == 0) handoff = tag;
        }
        __syncthreads();
    }
    out[b * TT + tid] = (float)tagbuf[tid];
}

// -------------------- launch --------------------
extern "C" void kernel_launch(void* const* d_in, const int* in_sizes, int n_in,
                              void* d_out, int out_size, void* d_ws, size_t ws_size,
                              hipStream_t stream) {
    const float* hid = (const float*)d_in[0];
    const int* mask = (const int*)d_in[1];
    const int* labels = (const int*)d_in[2];
    const float* Wm = (const float*)d_in[3];
    const float* bias = (const float*)d_in[4];
    const float* startT = (const float*)d_in[5];
    const float* endT = (const float*)d_in[6];
    const float* trans = (const float*)d_in[7];
    float* out = (float*)d_out;
    char* ws = (char*)d_ws;

    float* logits = (float*)ws;                              // 8,388,608 B
    float* shist = (float*)(ws + 8388608);                   // 8,388,608 B
    unsigned char* bp = (unsigned char*)(ws + 16777216);     // 2,097,152 B

    gemm_k<<<256, 512, 0, stream>>>(hid, Wm, bias, logits, out + BB * TT);
    scan_k<<<64, 64, 0, stream>>>(logits, mask, labels, startT, endT, trans, shist, out);
    bp_k<<<TT - 1, 256, 0, stream>>>(shist, trans, mask, bp);
    bt_k<<<BB, 512, 0, stream>>>(shist, endT, bp, out);
}

// Round 9
// 849.047 us; speedup vs baseline: 1.2795x; 1.2795x over previous
//
#include <hip/hip_runtime.h>
#include <hip/hip_bf16.h>
#include <math.h>

// Problem constants
#define BB 32
#define TT 512
#define HH 2048
#define KK 128
#define CH 16   // scan chunk (steps per emission-prefetch chunk)

// -------------------- Kernel A: logits = hiddens @ W + b --------------------
// 256 blocks x 512 threads, in-block split-K (4 wave-groups x K=512).
__global__ __launch_bounds__(512) void gemm_k(const float* __restrict__ hid,
                                              const float* __restrict__ Wm,
                                              const float* __restrict__ bias,
                                              float* __restrict__ logits,
                                              float* __restrict__ loss_slot) {
    __shared__ union {
        struct { float As[4][16][72]; float Bs[4][16][132]; } s;  // 52.2 KB
        float4 red[16][128];                                      // 32 KB
    } sm;
    const int tid = threadIdx.x, bid = blockIdx.x;
    if (bid == 0 && tid == 0) loss_slot[0] = 0.0f;
    const int g = tid >> 7, lt = tid & 127;
    const int rowBase = bid * 64;
    const int rowg = lt >> 4, colg = lt & 15;
    const int arow = lt >> 1, ahq = lt & 1;  // A staging: row, h-half

    float acc[8][8];
#pragma unroll
    for (int i = 0; i < 8; i++)
#pragma unroll
        for (int j = 0; j < 8; j++) acc[i][j] = 0.0f;

    const float* hA = hid + (size_t)(rowBase + arow) * HH + g * 512 + ahq * 8;

    float4 a0, a1, bv[4];
    {
        const int h0 = g * 512;
        a0 = *(const float4*)(hA);
        a1 = *(const float4*)(hA + 4);
#pragma unroll
        for (int r = 0; r < 4; ++r) {
            int idx = r * 128 + lt;
            bv[r] = *(const float4*)(Wm + (size_t)(h0 + (idx >> 5)) * KK + (idx & 31) * 4);
        }
    }

    for (int it = 0; it < 32; ++it) {
        __syncthreads();
        const int hb = ahq * 8;
        sm.s.As[g][hb + 0][arow] = a0.x;
        sm.s.As[g][hb + 1][arow] = a0.y;
        sm.s.As[g][hb + 2][arow] = a0.z;
        sm.s.As[g][hb + 3][arow] = a0.w;
        sm.s.As[g][hb + 4][arow] = a1.x;
        sm.s.As[g][hb + 5][arow] = a1.y;
        sm.s.As[g][hb + 6][arow] = a1.z;
        sm.s.As[g][hb + 7][arow] = a1.w;
#pragma unroll
        for (int r = 0; r < 4; ++r) {
            int idx = r * 128 + lt;
            *(float4*)&sm.s.Bs[g][idx >> 5][(idx & 31) * 4] = bv[r];
        }
        __syncthreads();
        if (it + 1 < 32) {
            const int h0 = g * 512 + (it + 1) * 16;
            a0 = *(const float4*)(hA + (it + 1) * 16);
            a1 = *(const float4*)(hA + (it + 1) * 16 + 4);
#pragma unroll
            for (int r = 0; r < 4; ++r) {
                int idx = r * 128 + lt;
                bv[r] = *(const float4*)(Wm + (size_t)(h0 + (idx >> 5)) * KK + (idx & 31) * 4);
            }
        }
#pragma unroll
        for (int h = 0; h < 16; ++h) {
            float4 aL = *(const float4*)&sm.s.As[g][h][rowg * 8];
            float4 aH = *(const float4*)&sm.s.As[g][h][rowg * 8 + 4];
            float4 b0 = *(const float4*)&sm.s.Bs[g][h][colg * 4];
            float4 b1 = *(const float4*)&sm.s.Bs[g][h][64 + colg * 4];
            float ar[8] = {aL.x, aL.y, aL.z, aL.w, aH.x, aH.y, aH.z, aH.w};
            float br[8] = {b0.x, b0.y, b0.z, b0.w, b1.x, b1.y, b1.z, b1.w};
#pragma unroll
            for (int i = 0; i < 8; i++)
#pragma unroll
                for (int j = 0; j < 8; j++) acc[i][j] = fmaf(ar[i], br[j], acc[i][j]);
        }
    }
    __syncthreads();
    for (int gp = 1; gp <= 3; ++gp) {
        if (g == gp) {
#pragma unroll
            for (int i = 0; i < 8; ++i) {
                sm.red[i * 2][lt] = make_float4(acc[i][0], acc[i][1], acc[i][2], acc[i][3]);
                sm.red[i * 2 + 1][lt] = make_float4(acc[i][4], acc[i][5], acc[i][6], acc[i][7]);
            }
        }
        __syncthreads();
        if (g == 0) {
#pragma unroll
            for (int i = 0; i < 8; ++i) {
                float4 r0 = sm.red[i * 2][lt];
                float4 r1 = sm.red[i * 2 + 1][lt];
                acc[i][0] += r0.x; acc[i][1] += r0.y; acc[i][2] += r0.z; acc[i][3] += r0.w;
                acc[i][4] += r1.x; acc[i][5] += r1.y; acc[i][6] += r1.z; acc[i][7] += r1.w;
            }
        }
        __syncthreads();
    }
    if (g == 0) {
        float4 bb0 = *(const float4*)(bias + colg * 4);
        float4 bb1 = *(const float4*)(bias + 64 + colg * 4);
#pragma unroll
        for (int i = 0; i < 8; ++i) {
            int row = rowBase + rowg * 8 + i;
            *(float4*)(logits + (size_t)row * KK + colg * 4) =
                make_float4(acc[i][0] + bb0.x, acc[i][1] + bb0.y, acc[i][2] + bb0.z, acc[i][3] + bb0.w);
            *(float4*)(logits + (size_t)row * KK + 64 + colg * 4) =
                make_float4(acc[i][4] + bb1.x, acc[i][5] + bb1.y, acc[i][6] + bb1.z, acc[i][7] + bb1.w);
        }
    }
}

// -------------------- Kernel B: sequential scans, 2 waves, 1 col/thread ------
// R9: 64 blocks x 128 threads. Thread j owns column j FULL-K: no cross-lane
// reduction at all (R2-R5's 240-cyc serial shfl pair is gone). V/T column
// resident in 128 VGPRs (fits — R6's 256+ spilled at the 184 cap). Alpha in
// 1KB double-buffered LDS; reads are uniform-address b128 broadcasts
// (conflict-free); ONE barrier per step across only 2 waves. Emissions and
// viterbi history in CH=16-step register chunks so vmcnt drains once/chunk.
struct SMemB {
    float sal[2][KK];
    float red[4];
};

__global__ __launch_bounds__(128, 1) void scan_k(const float* __restrict__ logits,
                                                 const int* __restrict__ mask,
                                                 const int* __restrict__ labels,
                                                 const float* __restrict__ startT,
                                                 const float* __restrict__ endT,
                                                 const float* __restrict__ trans,
                                                 float* __restrict__ shist,
                                                 float* __restrict__ out) {
    __shared__ SMemB sm;
    const int tid = threadIdx.x;      // 0..127, also the column j
    const int bid = blockIdx.x;
    const int lane = tid & 63, wv = tid >> 6;
    const float L2E = 1.4426950408889634f;
    const int j = tid;

    if (bid < BB) {
        // ---------- forward (log-partition), exp domain ----------
        const int b = bid;
        const float* lrow = logits + (size_t)b * TT * KK;
        unsigned long long mb[8];
#pragma unroll
        for (int c = 0; c < 8; ++c) mb[c] = __ballot(mask[b * TT + c * 64 + lane] != 0);

        float V[128];   // V[k] = exp2(trans[k][j] * L2E) — resident column
#pragma unroll
        for (int k = 0; k < 128; ++k) V[k] = exp2f(trans[(size_t)k * KK + j] * L2E);

        float OFF = (startT[0] + lrow[0]) * L2E;   // uniform across threads
        float S = exp2f((startT[j] + lrow[j]) * L2E - OFF);
        sm.sal[0][j] = S;
        int cur = 0;

        float emc[CH], emn[CH];
#pragma unroll
        for (int d = 0; d < CH; ++d) emc[d] = lrow[(size_t)d * KK + j];
        __syncthreads();

        for (int c = 0; c < TT / CH; ++c) {
            if (c + 1 < TT / CH) {
#pragma unroll
                for (int d = 0; d < CH; ++d)
                    emn[d] = lrow[(size_t)((c + 1) * CH + d) * KK + j];
            }
#pragma unroll
            for (int r = 0; r < CH; ++r) {
                const int t = c * CH + r;
                if (t > 0 && ((mb[t >> 6] >> (t & 63)) & 1ull)) {
                    const float4* base = (const float4*)sm.sal[cur];
                    float a0 = 0.f, a1 = 0.f, a2 = 0.f, a3 = 0.f;
                    float u0;
#pragma unroll
                    for (int i = 0; i < 32; ++i) {
                        float4 U = base[i];
                        if (i == 0) u0 = U.x;
                        a0 = fmaf(U.x, V[4 * i + 0], a0);
                        a1 = fmaf(U.y, V[4 * i + 1], a1);
                        a2 = fmaf(U.z, V[4 * i + 2], a2);
                        a3 = fmaf(U.w, V[4 * i + 3], a3);
                    }
                    float rinv = __builtin_amdgcn_rcpf(u0);
                    OFF += log2f(u0);   // off-chain, uniform
                    float w = (a0 + a1) + (a2 + a3);
                    S = w * (exp2f(emc[r] * L2E) * rinv);
                    sm.sal[cur ^ 1][j] = S;
                    cur ^= 1;
                    __syncthreads();
                }
            }
#pragma unroll
            for (int d = 0; d < CH; ++d) emc[d] = emn[d];
        }

        // final logZ: v_j = log2(S_j) + endT_j*L2E; reduce max then sum
        float v = log2f(S) + endT[j] * L2E;
        float mx = v;
#pragma unroll
        for (int d = 1; d < 64; d <<= 1) mx = fmaxf(mx, __shfl_xor(mx, d, 64));
        if (lane == 0) sm.red[wv] = mx;
        __syncthreads();
        mx = fmaxf(sm.red[0], sm.red[1]);
        float p = exp2f(v - mx);
#pragma unroll
        for (int d = 1; d < 64; d <<= 1) p += __shfl_xor(p, d, 64);
        if (lane == 0) sm.red[2 + wv] = p;

        // gold path score (parallel over t, 4 per thread)
        float part = 0.0f;
#pragma unroll
        for (int it = 0; it < 4; ++it) {
            int tt = tid + it * 128;
            if (tt == 0) {
                int l0 = labels[b * TT];
                part += startT[l0] + lrow[l0];
            } else if (mask[b * TT + tt]) {
                int lc = labels[b * TT + tt];
                int lp = labels[b * TT + tt - 1];
                part += trans[lp * KK + lc] + lrow[(size_t)tt * KK + lc];
            }
        }
#pragma unroll
        for (int d = 1; d < 64; d <<= 1) part += __shfl_xor(part, d, 64);
        __syncthreads();
        if (lane == 0) sm.red[wv] = part;
        __syncthreads();
        if (tid == 0) {
            int total = 0;
#pragma unroll
            for (int c = 0; c < 8; ++c) total += __popcll(mb[c]);
            float score = sm.red[0] + sm.red[1] + endT[labels[b * TT + total - 1]];
            float pp = sm.red[2] + sm.red[3];
            float logZ = (OFF + mx + log2f(pp)) * 0.6931471805599453f;
            float llh = score - logZ;
            atomicAdd(out + BB * TT, -llh * (1.0f / 32.0f));
        }
    } else {
        // ---------- viterbi forward (max only; score history -> ws) ----------
        const int b = bid - BB;
        const float* lrow = logits + (size_t)b * TT * KK;
        float* hist = shist + (size_t)b * TT * KK;
        unsigned long long mb[8];
#pragma unroll
        for (int c = 0; c < 8; ++c) mb[c] = __ballot(mask[b * TT + c * 64 + lane] != 0);

        float T[128];   // resident transition column
#pragma unroll
        for (int k = 0; k < 128; ++k) T[k] = trans[(size_t)k * KK + j];

        float S = startT[j] + lrow[j];
        sm.sal[0][j] = S;
        int cur = 0;

        float emc[CH], emn[CH], hb[CH];
#pragma unroll
        for (int d = 0; d < CH; ++d) emc[d] = lrow[(size_t)d * KK + j];
        __syncthreads();

        for (int c = 0; c < TT / CH; ++c) {
            if (c + 1 < TT / CH) {
#pragma unroll
                for (int d = 0; d < CH; ++d)
                    emn[d] = lrow[(size_t)((c + 1) * CH + d) * KK + j];
            }
#pragma unroll
            for (int r = 0; r < CH; ++r) {
                const int t = c * CH + r;
                if (t > 0 && ((mb[t >> 6] >> (t & 63)) & 1ull)) {
                    const float4* base = (const float4*)sm.sal[cur];
                    float m0 = -3.0e38f, m1 = -3.0e38f, m2 = -3.0e38f, m3 = -3.0e38f;
#pragma unroll
                    for (int i = 0; i < 32; ++i) {
                        float4 U = base[i];
                        float c0 = U.x + T[4 * i + 0];
                        float c1 = U.y + T[4 * i + 1];
                        float c2 = U.z + T[4 * i + 2];
                        float c3 = U.w + T[4 * i + 3];
                        m0 = fmaxf(m0, fmaxf(c0, c1));   // v_max3
                        m1 = fmaxf(m1, fmaxf(c2, c3));
                    }
                    m2 = fmaxf(m0, m1);
                    S = m2 + emc[r];
                    sm.sal[cur ^ 1][j] = S;
                    cur ^= 1;
                    __syncthreads();
                }
                hb[r] = S;
            }
            // flush chunk history (drains at next chunk's first barrier)
#pragma unroll
            for (int r = 0; r < CH; ++r)
                hist[(size_t)(c * CH + r) * KK + j] = hb[r];
#pragma unroll
            for (int d = 0; d < CH; ++d) emc[d] = emn[d];
        }
    }
}

// -------------------- Kernel C: parallel backpointer recompute --------------------
__global__ __launch_bounds__(256) void bp_k(const float* __restrict__ shist,
                                            const float* __restrict__ trans,
                                            const int* __restrict__ mask,
                                            unsigned char* __restrict__ bp) {
    const int t = blockIdx.x + 1;
    const int tid = threadIdx.x;
    const int j = tid & 127, bg = tid >> 7;
    __shared__ float sc[BB][KK];
#pragma unroll
    for (int r = 0; r < 4; ++r) {
        int f = tid + r * 256;
        int bb2 = f >> 5, c4 = (f & 31) * 4;
        *(float4*)&sc[bb2][c4] = *(const float4*)&shist[(size_t)bb2 * TT * KK + (size_t)(t - 1) * KK + c4];
    }
    __syncthreads();
    float m[16];
    int idx[16];
#pragma unroll
    for (int c = 0; c < 16; c++) { m[c] = -3.0e38f; idx[c] = 0; }
    for (int i4 = 0; i4 < 32; ++i4) {
        const int ib = i4 * 4;
        float tr0 = trans[(ib + 0) * KK + j];
        float tr1 = trans[(ib + 1) * KK + j];
        float tr2 = trans[(ib + 2) * KK + j];
        float tr3 = trans[(ib + 3) * KK + j];
#pragma unroll
        for (int c = 0; c < 16; c++) {
            float4 s4 = *(const float4*)&sc[bg + 2 * c][ib];
            float c0 = s4.x + tr0, c1 = s4.y + tr1, c2 = s4.z + tr2, c3 = s4.w + tr3;
            if (c0 > m[c]) { m[c] = c0; idx[c] = ib; }
            if (c1 > m[c]) { m[c] = c1; idx[c] = ib + 1; }
            if (c2 > m[c]) { m[c] = c2; idx[c] = ib + 2; }
            if (c3 > m[c]) { m[c] = c3; idx[c] = ib + 3; }
        }
    }
#pragma unroll
    for (int c = 0; c < 16; c++) {
        int bb2 = bg + 2 * c;
        int v = idx[c];
        if (mask[bb2 * TT + t] == 0) v = j;
        bp[(size_t)bb2 * TT * KK + (size_t)t * KK + j] = (unsigned char)v;
    }
}

// -------------------- Kernel D: backtrace via 8-wave register relay --------------------
__global__ __launch_bounds__(512) void bt_k(const float* __restrict__ shist,
                                            const float* __restrict__ endT,
                                            const unsigned char* __restrict__ bp,
                                            float* __restrict__ out) {
    const int b = blockIdx.x;
    const int tid = threadIdx.x;
    const int lane = tid & 63, w = tid >> 6;
    __shared__ float cb[128];
    __shared__ int tagbuf[512];
    __shared__ int handoff;
    if (tid < 128) cb[tid] = shist[(size_t)b * TT * KK + (size_t)(TT - 1) * KK + tid] + endT[tid];
    __syncthreads();
    if (tid == 0) {
        float mm = cb[0];
        int bi = 0;
        for (int i = 1; i < 128; i++)
            if (cb[i] > mm) { mm = cb[i]; bi = i; }
        tagbuf[TT - 1] = bi;
        handoff = bi;
    }
    unsigned int reg[64];
    const unsigned char* bpb = bp + (size_t)b * TT * KK;
#pragma unroll
    for (int r = 0; r < 64; r++) {
        int t_row = w * 64 + 1 + r;
        unsigned int v = 0;
        if (t_row < TT) v = *(const unsigned short*)(bpb + (size_t)t_row * KK + lane * 2);
        reg[r] = v;
    }
    __syncthreads();
    for (int ph = 7; ph >= 0; --ph) {
        if (w == ph) {
            int tag = handoff;
#pragma unroll
            for (int r = 63; r >= 0; --r) {
                int t_row = ph * 64 + 1 + r;
                if (t_row < TT) {
                    unsigned int vv = (unsigned int)__shfl((int)reg[r], tag >> 1, 64);
                    tag = (int)((vv >> ((tag & 1) * 8)) & 0xffu);
                    if (lane == 0) tagbuf[t_row - 1] = tag;
                }
            }
            if (lane == 0) handoff = tag;
        }
        __syncthreads();
    }
    out[b * TT + tid] = (float)tagbuf[tid];
}

// -------------------- launch --------------------
extern "C" void kernel_launch(void* const* d_in, const int* in_sizes, int n_in,
                              void* d_out, int out_size, void* d_ws, size_t ws_size,
                              hipStream_t stream) {
    const float* hid = (const float*)d_in[0];
    const int* mask = (const int*)d_in[1];
    const int* labels = (const int*)d_in[2];
    const float* Wm = (const float*)d_in[3];
    const float* bias = (const float*)d_in[4];
    const float* startT = (const float*)d_in[5];
    const float* endT = (const float*)d_in[6];
    const float* trans = (const float*)d_in[7];
    float* out = (float*)d_out;
    char* ws = (char*)d_ws;

    float* logits = (float*)ws;                              // 8,388,608 B
    float* shist = (float*)(ws + 8388608);                   // 8,388,608 B
    unsigned char* bp = (unsigned char*)(ws + 16777216);     // 2,097,152 B

    gemm_k<<<256, 512, 0, stream>>>(hid, Wm, bias, logits, out + BB * TT);
    scan_k<<<64, 128, 0, stream>>>(logits, mask, labels, startT, endT, trans, shist, out);
    bp_k<<<TT - 1, 256, 0, stream>>>(shist, trans, mask, bp);
    bt_k<<<BB, 512, 0, stream>>>(shist, endT, bp, out);
}

// Round 10
// 620.124 us; speedup vs baseline: 1.7518x; 1.3692x over previous
//
#include <hip/hip_runtime.h>
#include <hip/hip_bf16.h>
#include <math.h>

// Problem constants
#define BB 32
#define TT 512
#define HH 2048
#define KK 128
#define CH 8   // scan chunk (steps per emission-prefetch chunk)

// DPP quad-lane reductions (lanes tid&3 = 0..3 hold k-slice partials).
// quad_perm xor1 = [1,0,3,2] -> ctrl 0xB1 ; xor2 = [2,3,0,1] -> ctrl 0x4E.
// VALU pipe (~5 cyc) vs ds_swizzle shfl (~120 cyc) — the R2-R5 chain killer.
__device__ __forceinline__ float quad_add(float x) {
    int a = __builtin_amdgcn_update_dpp(0, __float_as_int(x), 0xB1, 0xF, 0xF, true);
    x += __int_as_float(a);
    int b = __builtin_amdgcn_update_dpp(0, __float_as_int(x), 0x4E, 0xF, 0xF, true);
    x += __int_as_float(b);
    return x;
}
__device__ __forceinline__ float quad_max(float x) {
    int a = __builtin_amdgcn_update_dpp(0, __float_as_int(x), 0xB1, 0xF, 0xF, true);
    x = fmaxf(x, __int_as_float(a));
    int b = __builtin_amdgcn_update_dpp(0, __float_as_int(x), 0x4E, 0xF, 0xF, true);
    x = fmaxf(x, __int_as_float(b));
    return x;
}

// -------------------- Kernel A: logits = hiddens @ W + b --------------------
// 256 blocks x 512 threads, in-block split-K (4 wave-groups x K=512).
__global__ __launch_bounds__(512) void gemm_k(const float* __restrict__ hid,
                                              const float* __restrict__ Wm,
                                              const float* __restrict__ bias,
                                              float* __restrict__ logits,
                                              float* __restrict__ loss_slot) {
    __shared__ union {
        struct { float As[4][16][72]; float Bs[4][16][132]; } s;  // 52.2 KB
        float4 red[16][128];                                      // 32 KB
    } sm;
    const int tid = threadIdx.x, bid = blockIdx.x;
    if (bid == 0 && tid == 0) loss_slot[0] = 0.0f;
    const int g = tid >> 7, lt = tid & 127;
    const int rowBase = bid * 64;
    const int rowg = lt >> 4, colg = lt & 15;
    const int arow = lt >> 1, ahq = lt & 1;  // A staging: row, h-half

    float acc[8][8];
#pragma unroll
    for (int i = 0; i < 8; i++)
#pragma unroll
        for (int j = 0; j < 8; j++) acc[i][j] = 0.0f;

    const float* hA = hid + (size_t)(rowBase + arow) * HH + g * 512 + ahq * 8;

    float4 a0, a1, bv[4];
    {
        const int h0 = g * 512;
        a0 = *(const float4*)(hA);
        a1 = *(const float4*)(hA + 4);
#pragma unroll
        for (int r = 0; r < 4; ++r) {
            int idx = r * 128 + lt;
            bv[r] = *(const float4*)(Wm + (size_t)(h0 + (idx >> 5)) * KK + (idx & 31) * 4);
        }
    }

    for (int it = 0; it < 32; ++it) {
        __syncthreads();
        const int hb = ahq * 8;
        sm.s.As[g][hb + 0][arow] = a0.x;
        sm.s.As[g][hb + 1][arow] = a0.y;
        sm.s.As[g][hb + 2][arow] = a0.z;
        sm.s.As[g][hb + 3][arow] = a0.w;
        sm.s.As[g][hb + 4][arow] = a1.x;
        sm.s.As[g][hb + 5][arow] = a1.y;
        sm.s.As[g][hb + 6][arow] = a1.z;
        sm.s.As[g][hb + 7][arow] = a1.w;
#pragma unroll
        for (int r = 0; r < 4; ++r) {
            int idx = r * 128 + lt;
            *(float4*)&sm.s.Bs[g][idx >> 5][(idx & 31) * 4] = bv[r];
        }
        __syncthreads();
        if (it + 1 < 32) {
            const int h0 = g * 512 + (it + 1) * 16;
            a0 = *(const float4*)(hA + (it + 1) * 16);
            a1 = *(const float4*)(hA + (it + 1) * 16 + 4);
#pragma unroll
            for (int r = 0; r < 4; ++r) {
                int idx = r * 128 + lt;
                bv[r] = *(const float4*)(Wm + (size_t)(h0 + (idx >> 5)) * KK + (idx & 31) * 4);
            }
        }
#pragma unroll
        for (int h = 0; h < 16; ++h) {
            float4 aL = *(const float4*)&sm.s.As[g][h][rowg * 8];
            float4 aH = *(const float4*)&sm.s.As[g][h][rowg * 8 + 4];
            float4 b0 = *(const float4*)&sm.s.Bs[g][h][colg * 4];
            float4 b1 = *(const float4*)&sm.s.Bs[g][h][64 + colg * 4];
            float ar[8] = {aL.x, aL.y, aL.z, aL.w, aH.x, aH.y, aH.z, aH.w};
            float br[8] = {b0.x, b0.y, b0.z, b0.w, b1.x, b1.y, b1.z, b1.w};
#pragma unroll
            for (int i = 0; i < 8; i++)
#pragma unroll
                for (int j = 0; j < 8; j++) acc[i][j] = fmaf(ar[i], br[j], acc[i][j]);
        }
    }
    __syncthreads();
    for (int gp = 1; gp <= 3; ++gp) {
        if (g == gp) {
#pragma unroll
            for (int i = 0; i < 8; ++i) {
                sm.red[i * 2][lt] = make_float4(acc[i][0], acc[i][1], acc[i][2], acc[i][3]);
                sm.red[i * 2 + 1][lt] = make_float4(acc[i][4], acc[i][5], acc[i][6], acc[i][7]);
            }
        }
        __syncthreads();
        if (g == 0) {
#pragma unroll
            for (int i = 0; i < 8; ++i) {
                float4 r0 = sm.red[i * 2][lt];
                float4 r1 = sm.red[i * 2 + 1][lt];
                acc[i][0] += r0.x; acc[i][1] += r0.y; acc[i][2] += r0.z; acc[i][3] += r0.w;
                acc[i][4] += r1.x; acc[i][5] += r1.y; acc[i][6] += r1.z; acc[i][7] += r1.w;
            }
        }
        __syncthreads();
    }
    if (g == 0) {
        float4 bb0 = *(const float4*)(bias + colg * 4);
        float4 bb1 = *(const float4*)(bias + 64 + colg * 4);
#pragma unroll
        for (int i = 0; i < 8; ++i) {
            int row = rowBase + rowg * 8 + i;
            *(float4*)(logits + (size_t)row * KK + colg * 4) =
                make_float4(acc[i][0] + bb0.x, acc[i][1] + bb0.y, acc[i][2] + bb0.z, acc[i][3] + bb0.w);
            *(float4*)(logits + (size_t)row * KK + 64 + colg * 4) =
                make_float4(acc[i][4] + bb1.x, acc[i][5] + bb1.y, acc[i][6] + bb1.z, acc[i][7] + bb1.w);
        }
    }
}

// -------------------- Kernel B: sequential scans (R5 structure + DPP) --------
// 64 blocks x 256 threads. Thread (jb=tid>>2, s=tid&3) owns cols {2jb,2jb+1},
// k-slice [32s,32s+32). V/T = 64 regs (PROVEN no-spill: R2-R5 ran at VGPR
// 72-76; R6/R9's 128-256-reg arrays spilled). Cross-slice reduction via DPP
// quad_perm (VALU, ~5cyc) instead of shfl_xor (DS pipe, ~120cyc x2 serial).
// Emissions: CH=8-step global register ring (one vmcnt drain per chunk).
// Viterbi history buffered 8 steps, flushed per chunk.
struct SMemB {
    float ubuf[2][144];
    float red[4];
    float vbuf[128];
};

__global__ __launch_bounds__(256, 1) void scan_k(const float* __restrict__ logits,
                                                 const int* __restrict__ mask,
                                                 const int* __restrict__ labels,
                                                 const float* __restrict__ startT,
                                                 const float* __restrict__ endT,
                                                 const float* __restrict__ trans,
                                                 float* __restrict__ shist,
                                                 float* __restrict__ out) {
    __shared__ SMemB sm;
    const int tid = threadIdx.x;
    const int bid = blockIdx.x;
    const float L2E = 1.4426950408889634f;
    const int s = tid & 3;
    const int jb = tid >> 2;
    const int j0 = jb * 2;
    const int padw = j0 + 4 * (j0 >> 5);
    const int lane = tid & 63;
    const int NCHUNK = TT / CH;  // 64

    if (bid < BB) {
        // ---------- forward (log-partition), exp domain ----------
        const int b = bid;
        const float* lrow = logits + (size_t)b * TT * KK;
        unsigned long long mb[8];
#pragma unroll
        for (int c = 0; c < 8; ++c) mb[c] = __ballot(mask[b * TT + c * 64 + lane] != 0);
        float V0[32], V1[32];
#pragma unroll
        for (int k = 0; k < 32; k++) {
            V0[k] = exp2f(trans[(s * 32 + k) * KK + j0] * L2E);
            V1[k] = exp2f(trans[(s * 32 + k) * KK + j0 + 1] * L2E);
        }
        float a0_ = (startT[j0] + lrow[j0]) * L2E;
        float a1_ = (startT[j0 + 1] + lrow[j0 + 1]) * L2E;
        float OFF = (startT[0] + lrow[0]) * L2E;  // identical on all threads
        float S0_ = exp2f(a0_ - OFF);
        float S1_ = exp2f(a1_ - OFF);
        if (s == 0) {
            sm.ubuf[0][padw] = S0_;
            sm.ubuf[0][padw + 1] = S1_;
        }
        float2 emc[CH], emn[CH];
#pragma unroll
        for (int d = 0; d < CH; ++d) emc[d] = *(const float2*)(lrow + (size_t)d * KK + j0);
        __syncthreads();
        int cur = 0;
        for (int c = 0; c < NCHUNK; ++c) {
#pragma unroll
            for (int r = 0; r < CH; ++r) {
                const int t = c * CH + r;
                if (r == 0 && c + 1 < NCHUNK) {
#pragma unroll
                    for (int d = 0; d < CH; ++d)
                        emn[d] = *(const float2*)(lrow + (size_t)((c + 1) * CH + d) * KK + j0);
                }
                if (t > 0 && ((mb[t >> 6] >> (t & 63)) & 1ull)) {
                    const float* ub = &sm.ubuf[cur][s * 36];
                    float u00 = sm.ubuf[cur][0];
                    float uu[32];
#pragma unroll
                    for (int cc = 0; cc < 8; ++cc) {
                        float4 v = *(const float4*)(ub + cc * 4);
                        uu[cc * 4] = v.x; uu[cc * 4 + 1] = v.y; uu[cc * 4 + 2] = v.z; uu[cc * 4 + 3] = v.w;
                    }
                    float2 em = emc[r];
                    float p0e = 0.f, p0o = 0.f, p1e = 0.f, p1o = 0.f;
#pragma unroll
                    for (int k = 0; k < 32; k += 2) {
                        p0e = fmaf(uu[k], V0[k], p0e);
                        p1e = fmaf(uu[k], V1[k], p1e);
                        p0o = fmaf(uu[k + 1], V0[k + 1], p0o);
                        p1o = fmaf(uu[k + 1], V1[k + 1], p1o);
                    }
                    float w0 = quad_add(p0e + p0o);
                    float w1 = quad_add(p1e + p1o);
                    float rinv = __builtin_amdgcn_rcpf(u00);
                    OFF += log2f(u00);  // off-chain, uniform across threads
                    S0_ = w0 * (exp2f(em.x * L2E) * rinv);
                    S1_ = w1 * (exp2f(em.y * L2E) * rinv);
                    if (s == 0) {
                        sm.ubuf[cur ^ 1][padw] = S0_;
                        sm.ubuf[cur ^ 1][padw + 1] = S1_;
                    }
                    cur ^= 1;
                }
                __syncthreads();
            }
#pragma unroll
            for (int d = 0; d < CH; ++d) emc[d] = emn[d];
        }
        if (s == 0) {
            sm.vbuf[j0] = log2f(S0_) + endT[j0] * L2E;
            sm.vbuf[j0 + 1] = log2f(S1_) + endT[j0 + 1] * L2E;
        }
        __syncthreads();

        // gold path score (parallel over t)
        float part = 0.0f;
        for (int tt = tid; tt < TT; tt += 256) {
            if (tt == 0) {
                int l0 = labels[b * TT];
                part += startT[l0] + lrow[l0];
            } else if (mask[b * TT + tt]) {
                int lc = labels[b * TT + tt];
                int lp = labels[b * TT + tt - 1];
                part += trans[lp * KK + lc] + lrow[(size_t)tt * KK + lc];
            }
        }
#pragma unroll
        for (int d = 1; d < 64; d <<= 1) part += __shfl_xor(part, d, 64);
        int wid = tid >> 6;
        if (lane == 0) sm.red[wid] = part;
        __syncthreads();
        if (tid < 64) {
            float v0 = sm.vbuf[tid], v1 = sm.vbuf[tid + 64];
            float mx = fmaxf(v0, v1);
#pragma unroll
            for (int d = 1; d < 64; d <<= 1) mx = fmaxf(mx, __shfl_xor(mx, d, 64));
            float p = exp2f(v0 - mx) + exp2f(v1 - mx);
#pragma unroll
            for (int d = 1; d < 64; d <<= 1) p += __shfl_xor(p, d, 64);
            if (tid == 0) {
                int total = 0;
#pragma unroll
                for (int c = 0; c < 8; ++c) total += __popcll(mb[c]);
                float score = sm.red[0] + sm.red[1] + sm.red[2] + sm.red[3];
                score += endT[labels[b * TT + total - 1]];
                float logZ = (OFF + mx + log2f(p)) * 0.6931471805599453f;
                float llh = score - logZ;
                atomicAdd(out + BB * TT, -llh * (1.0f / 32.0f));
            }
        }
    } else {
        // ---------- viterbi forward (max only; score history -> ws) ----------
        const int b = bid - BB;
        const float* lrow = logits + (size_t)b * TT * KK;
        float* hist = shist + (size_t)b * TT * KK;
        unsigned long long mb[8];
#pragma unroll
        for (int c = 0; c < 8; ++c) mb[c] = __ballot(mask[b * TT + c * 64 + lane] != 0);
        float T0[32], T1[32];
#pragma unroll
        for (int k = 0; k < 32; k++) {
            T0[k] = trans[(s * 32 + k) * KK + j0];
            T1[k] = trans[(s * 32 + k) * KK + j0 + 1];
        }
        float s0_ = startT[j0] + lrow[j0];
        float s1_ = startT[j0 + 1] + lrow[j0 + 1];
        if (s == 0) {
            sm.ubuf[0][padw] = s0_;
            sm.ubuf[0][padw + 1] = s1_;
        } else if (s == 1) {
            *(float2*)(hist + j0) = make_float2(s0_, s1_);
        }
        float2 emc[CH], emn[CH], hb[CH];
#pragma unroll
        for (int d = 0; d < CH; ++d) emc[d] = *(const float2*)(lrow + (size_t)d * KK + j0);
        __syncthreads();
        int cur = 0;
        for (int c = 0; c < NCHUNK; ++c) {
#pragma unroll
            for (int r = 0; r < CH; ++r) {
                const int t = c * CH + r;
                if (r == 0 && c + 1 < NCHUNK) {
#pragma unroll
                    for (int d = 0; d < CH; ++d)
                        emn[d] = *(const float2*)(lrow + (size_t)((c + 1) * CH + d) * KK + j0);
                }
                if (t > 0 && ((mb[t >> 6] >> (t & 63)) & 1ull)) {
                    const float* ub = &sm.ubuf[cur][s * 36];
                    float uu[32];
#pragma unroll
                    for (int cc = 0; cc < 8; ++cc) {
                        float4 v = *(const float4*)(ub + cc * 4);
                        uu[cc * 4] = v.x; uu[cc * 4 + 1] = v.y; uu[cc * 4 + 2] = v.z; uu[cc * 4 + 3] = v.w;
                    }
                    float2 em = emc[r];
                    float m0a = -3.0e38f, m0b = -3.0e38f, m1a = -3.0e38f, m1b = -3.0e38f;
#pragma unroll
                    for (int k = 0; k < 32; k += 4) {
                        m0a = fmaxf(m0a, fmaxf(uu[k] + T0[k], uu[k + 1] + T0[k + 1]));
                        m0b = fmaxf(m0b, fmaxf(uu[k + 2] + T0[k + 2], uu[k + 3] + T0[k + 3]));
                        m1a = fmaxf(m1a, fmaxf(uu[k] + T1[k], uu[k + 1] + T1[k + 1]));
                        m1b = fmaxf(m1b, fmaxf(uu[k + 2] + T1[k + 2], uu[k + 3] + T1[k + 3]));
                    }
                    float m0 = quad_max(fmaxf(m0a, m0b));
                    float m1 = quad_max(fmaxf(m1a, m1b));
                    s0_ = m0 + em.x;
                    s1_ = m1 + em.y;
                    if (s == 0) {
                        sm.ubuf[cur ^ 1][padw] = s0_;
                        sm.ubuf[cur ^ 1][padw + 1] = s1_;
                    }
                    cur ^= 1;
                }
                hb[r] = make_float2(s0_, s1_);
                __syncthreads();
            }
            // flush this chunk's history rows (stores drain at a later barrier;
            // one ack-wait per chunk, not per step)
            if (s == 1) {
#pragma unroll
                for (int r = 0; r < CH; ++r)
                    *(float2*)(hist + (size_t)(c * CH + r) * KK + j0) = hb[r];
            }
#pragma unroll
            for (int d = 0; d < CH; ++d) emc[d] = emn[d];
        }
    }
}

// -------------------- Kernel C: parallel backpointer recompute --------------------
__global__ __launch_bounds__(256) void bp_k(const float* __restrict__ shist,
                                            const float* __restrict__ trans,
                                            const int* __restrict__ mask,
                                            unsigned char* __restrict__ bp) {
    const int t = blockIdx.x + 1;
    const int tid = threadIdx.x;
    const int j = tid & 127, bg = tid >> 7;
    __shared__ float sc[BB][KK];
#pragma unroll
    for (int r = 0; r < 4; ++r) {
        int f = tid + r * 256;
        int bb2 = f >> 5, c4 = (f & 31) * 4;
        *(float4*)&sc[bb2][c4] = *(const float4*)&shist[(size_t)bb2 * TT * KK + (size_t)(t - 1) * KK + c4];
    }
    __syncthreads();
    float m[16];
    int idx[16];
#pragma unroll
    for (int c = 0; c < 16; c++) { m[c] = -3.0e38f; idx[c] = 0; }
    for (int i4 = 0; i4 < 32; ++i4) {
        const int ib = i4 * 4;
        float tr0 = trans[(ib + 0) * KK + j];
        float tr1 = trans[(ib + 1) * KK + j];
        float tr2 = trans[(ib + 2) * KK + j];
        float tr3 = trans[(ib + 3) * KK + j];
#pragma unroll
        for (int c = 0; c < 16; c++) {
            float4 s4 = *(const float4*)&sc[bg + 2 * c][ib];
            float c0 = s4.x + tr0, c1 = s4.y + tr1, c2 = s4.z + tr2, c3 = s4.w + tr3;
            if (c0 > m[c]) { m[c] = c0; idx[c] = ib; }
            if (c1 > m[c]) { m[c] = c1; idx[c] = ib + 1; }
            if (c2 > m[c]) { m[c] = c2; idx[c] = ib + 2; }
            if (c3 > m[c]) { m[c] = c3; idx[c] = ib + 3; }
        }
    }
#pragma unroll
    for (int c = 0; c < 16; c++) {
        int bb2 = bg + 2 * c;
        int v = idx[c];
        if (mask[bb2 * TT + t] == 0) v = j;
        bp[(size_t)bb2 * TT * KK + (size_t)t * KK + j] = (unsigned char)v;
    }
}

// -------------------- Kernel D: backtrace via 8-wave register relay --------------------
__global__ __launch_bounds__(512) void bt_k(const float* __restrict__ shist,
                                            const float* __restrict__ endT,
                                            const unsigned char* __restrict__ bp,
                                            float* __restrict__ out) {
    const int b = blockIdx.x;
    const int tid = threadIdx.x;
    const int lane = tid & 63, w = tid >> 6;
    __shared__ float cb[128];
    __shared__ int tagbuf[512];
    __shared__ int handoff;
    if (tid < 128) cb[tid] = shist[(size_t)b * TT * KK + (size_t)(TT - 1) * KK + tid] + endT[tid];
    __syncthreads();
    if (tid == 0) {
        float mm = cb[0];
        int bi = 0;
        for (int i = 1; i < 128; i++)
            if (cb[i] > mm) { mm = cb[i]; bi = i; }
        tagbuf[TT - 1] = bi;
        handoff = bi;
    }
    unsigned int reg[64];
    const unsigned char* bpb = bp + (size_t)b * TT * KK;
#pragma unroll
    for (int r = 0; r < 64; r++) {
        int t_row = w * 64 + 1 + r;
        unsigned int v = 0;
        if (t_row < TT) v = *(const unsigned short*)(bpb + (size_t)t_row * KK + lane * 2);
        reg[r] = v;
    }
    __syncthreads();
    for (int ph = 7; ph >= 0; --ph) {
        if (w == ph) {
            int tag = handoff;
#pragma unroll
            for (int r = 63; r >= 0; --r) {
                int t_row = ph * 64 + 1 + r;
                if (t_row < TT) {
                    unsigned int vv = (unsigned int)__shfl((int)reg[r], tag >> 1, 64);
                    tag = (int)((vv >> ((tag & 1) * 8)) & 0xffu);
                    if (lane == 0) tagbuf[t_row - 1] = tag;
                }
            }
            if (lane == 0) handoff = tag;
        }
        __syncthreads();
    }
    out[b * TT + tid] = (float)tagbuf[tid];
}

// -------------------- launch --------------------
extern "C" void kernel_launch(void* const* d_in, const int* in_sizes, int n_in,
                              void* d_out, int out_size, void* d_ws, size_t ws_size,
                              hipStream_t stream) {
    const float* hid = (const float*)d_in[0];
    const int* mask = (const int*)d_in[1];
    const int* labels = (const int*)d_in[2];
    const float* Wm = (const float*)d_in[3];
    const float* bias = (const float*)d_in[4];
    const float* startT = (const float*)d_in[5];
    const float* endT = (const float*)d_in[6];
    const float* trans = (const float*)d_in[7];
    float* out = (float*)d_out;
    char* ws = (char*)d_ws;

    float* logits = (float*)ws;                              // 8,388,608 B
    float* shist = (float*)(ws + 8388608);                   // 8,388,608 B
    unsigned char* bp = (unsigned char*)(ws + 16777216);     // 2,097,152 B

    gemm_k<<<256, 512, 0, stream>>>(hid, Wm, bias, logits, out + BB * TT);
    scan_k<<<64, 256, 0, stream>>>(logits, mask, labels, startT, endT, trans, shist, out);
    bp_k<<<TT - 1, 256, 0, stream>>>(shist, trans, mask, bp);
    bt_k<<<BB, 512, 0, stream>>>(shist, endT, bp, out);
}